// Round 6
// baseline (520.692 us; speedup 1.0000x reference)
//
#include <hip/hip_runtime.h>
#include <hip/hip_bf16.h>
#include <math.h>

// Problem constants
#define BB 8
#define LL 8192
#define DD 512
#define NROWS (BB * LL)  // 65536

// d_out layout (floats)
#define OUT_COMP   0
#define OUT_MASK   33554432
#define OUT_BHARD  33619968
#define OUT_P      33685504
#define OUT_PCOMP  33751040
#define OUT_LOSS   33816576

// ws layout (bytes)
#define WS_FIXLIST 0         // 65536*4
#define WS_FIXCNT  262144    // 4
#define WS_COUNTS  262148    // 32
#define WS_SUMP    262180    // 32
#define WS_SEL     262212    // 65536*4 -> 524356
#define WS_SSK     524416    // 65536*4
#define WS_SSQ     786560    // 65536*4
#define WS_DOT     1048704   // 65536*4
#define WS_WQH     1310848   // 512 KB each
#define WS_WKH     1835136   // end ~2.4 MB

#define FIX_CAP 65536
// 2-pairing cos error rms ~2e-6; 5e-5 = 25 sigma flip margin.
#define FIX_TAU 5e-5f

typedef __attribute__((ext_vector_type(8))) _Float16 half8;
typedef __attribute__((ext_vector_type(4))) float f32x4;

// ---------------------------------------------------------------------------
// Pass 0: split Wq,Wk into f16 hi (2-pairing GEMM: A hi/lo x B hi),
// fragment-chunk order: chunk c = (kt*32 + ct)*64 + kblk*16 + n holds
// W[e = ct*16+n][d = kt*32 + kblk*8 .. +8]. Also zero-inits accumulators.
// This order makes a lane's B-fragment a contiguous 16 B global load.
// ---------------------------------------------------------------------------
__global__ __launch_bounds__(256) void wsplit(
    const float* __restrict__ Wq, const float* __restrict__ Wk,
    _Float16* __restrict__ wqh, _Float16* __restrict__ wkh,
    float* __restrict__ ssk, float* __restrict__ ssq,
    float* __restrict__ dotb, int* __restrict__ fixcnt) {
  const int t = blockIdx.x * 256 + threadIdx.x;  // 0..65535
  if (t == 0) *fixcnt = 0;
  ssk[t] = 0.0f;
  ssq[t] = 0.0f;
  dotb[t] = 0.0f;

  const int m = t >> 15;         // 0 = Wq, 1 = Wk
  const int c = t & 32767;       // chunk id
  const int kt = c >> 11;
  const int ct = (c >> 6) & 31;
  const int l = c & 63;
  const int n = l & 15;
  const int kblk = l >> 4;
  const int e = ct * 16 + n;
  const int d0 = kt * 32 + kblk * 8;
  const float* src = (m ? Wk : Wq) + (long)e * 512 + d0;
  _Float16* dh = (m ? wkh : wqh) + (long)c * 8;
  float4 v0 = *(const float4*)src;
  float4 v1 = *(const float4*)(src + 4);
  float av[8] = {v0.x, v0.y, v0.z, v0.w, v1.x, v1.y, v1.z, v1.w};
  half8 hi;
#pragma unroll
  for (int j = 0; j < 8; ++j) hi[j] = (_Float16)av[j];
  *(half8*)dh = hi;
}

// ---------------------------------------------------------------------------
// FUSED GEMM: q = x*Wq^T and k = x*Wk^T. 128x128 tile, BK=32.
// OCCUPANCY build: 512 threads = 8 waves (2 wrow x 4 wcol), per-wave output
// 64x32 per GEMM -> acc = 64 regs/wave (was 128). __launch_bounds__(512,4)
// pins VGPR<=128 -> 4 waves/SIMD (2 independent blocks/CU), doubling the
// latency-hiding pool (rounds 4/5 proved LDS traffic & vmcnt pipelining are
// not the limiter at 2 waves/SIMD; occupancy is the remaining lever).
//  - A: f16 hi/lo staged to LDS by 512 threads (1 chunk each: 2 f32x4 loads,
//    convert, 2 ds_write_b128), double-buffered (32 KB).
//  - B: global->reg (fragment-chunk order, L2-resident), 2 nb x 2 GEMMs,
//    reloaded right after last use each step.
//  - Barrier: lgkmcnt(0)+s_barrier only; NO g2l -> all global loads stay
//    in flight across barriers, no vmcnt bookkeeping at all.
// ---------------------------------------------------------------------------
__global__ __launch_bounds__(512, 4) void gemm_fused(
    const float* __restrict__ x,
    const _Float16* __restrict__ wqh, const _Float16* __restrict__ wkh,
    float* __restrict__ ssqOut, float* __restrict__ sskOut,
    float* __restrict__ dotOut,
    float* __restrict__ qedge, float* __restrict__ kedge) {
  __shared__ _Float16 smem[17408];  // 34816 B (epilogue KX = 128*136 halfs)
  _Float16* AH0 = smem;             // chunks: (mbs*64 + kblk*16 + ms)
  _Float16* AL0 = smem + 4096;
  _Float16* AH1 = smem + 8192;
  _Float16* AL1 = smem + 12288;

  const int tid = threadIdx.x;
  const int lane = tid & 63;
  const int w = tid >> 6;          // 0..7
  const int wrow = w & 1, wcol = w >> 1;  // wcol 0..3
  const int g = lane >> 4, n = lane & 15;
  const int bx0 = blockIdx.x;
  const int bx = ((bx0 & 7) << 8) | (bx0 >> 3);  // XCD-contiguous (2048 = 8*256)
  const int rb = bx >> 2, cb = bx & 3;
  const long r0 = (long)rb * 128;

  // A staging: thread tid = chunk c: mbs = tid>>6, kblk = (tid>>4)&3,
  // ms = tid&15 -> row = mbs*16+ms, cols kblk*8..+8 (+ kt*32).
  const int arow = ((tid >> 6) << 4) | (tid & 15);
  const int akb = (tid >> 4) & 3;
  const float* ap = x + (r0 + arow) * 512 + akb * 8;

  // B fragment base: ct = cb*8 + wcol*2 (+nb); 16 B per lane, kt stride 16384.
  const _Float16* bqb = wqh + ((long)((cb * 8 + wcol * 2) * 64 + lane)) * 8;
  const _Float16* bkb = wkh + ((long)((cb * 8 + wcol * 2) * 64 + lane)) * 8;

  f32x4 accq[4][2], acck[4][2];
#pragma unroll
  for (int mb = 0; mb < 4; ++mb)
#pragma unroll
    for (int nb = 0; nb < 2; ++nb) {
      accq[mb][nb] = (f32x4){0.f, 0.f, 0.f, 0.f};
      acck[mb][nb] = (f32x4){0.f, 0.f, 0.f, 0.f};
    }

  half8 bq[2], bk[2];  // persistent B set (16 VGPR)

#define LOAD_B_ALL(ktv)                                                   \
  do {                                                                    \
    _Pragma("unroll") for (int nb = 0; nb < 2; ++nb) {                    \
      bq[nb] = *(const half8*)(bqb + (long)(ktv)*16384 + nb * 512);       \
      bk[nb] = *(const half8*)(bkb + (long)(ktv)*16384 + nb * 512);       \
    }                                                                     \
  } while (0)

#define CONV_A(F0, F1, AH_, AL_)                                          \
  do {                                                                    \
    float av[8] = {F0.x, F0.y, F0.z, F0.w, F1.x, F1.y, F1.z, F1.w};       \
    half8 h, lo;                                                          \
    _Pragma("unroll") for (int j = 0; j < 8; ++j) {                       \
      _Float16 a = (_Float16)av[j];                                       \
      h[j] = a;                                                           \
      lo[j] = (_Float16)(av[j] - (float)a);                               \
    }                                                                     \
    *(half8*)((AH_) + tid * 8) = h;                                       \
    *(half8*)((AL_) + tid * 8) = lo;                                      \
  } while (0)

  // COMPUTE: per mb {2 ds_read_b128, 8 MFMA}; after all, reload B for KTN.
#define COMPUTE(AH_, AL_, KTN)                                            \
  do {                                                                    \
    _Pragma("unroll") for (int mb = 0; mb < 4; ++mb) {                    \
      const int aoff = ((wrow * 4 + mb) * 64 + lane) * 8;                 \
      half8 ah = *(const half8*)((AH_) + aoff);                           \
      half8 al = *(const half8*)((AL_) + aoff);                           \
      __builtin_amdgcn_s_setprio(1);                                      \
      _Pragma("unroll") for (int nb = 0; nb < 2; ++nb) {                  \
        accq[mb][nb] = __builtin_amdgcn_mfma_f32_16x16x32_f16(            \
            ah, bq[nb], accq[mb][nb], 0, 0, 0);                           \
        acck[mb][nb] = __builtin_amdgcn_mfma_f32_16x16x32_f16(            \
            ah, bk[nb], acck[mb][nb], 0, 0, 0);                           \
        accq[mb][nb] = __builtin_amdgcn_mfma_f32_16x16x32_f16(            \
            al, bq[nb], accq[mb][nb], 0, 0, 0);                           \
        acck[mb][nb] = __builtin_amdgcn_mfma_f32_16x16x32_f16(            \
            al, bk[nb], acck[mb][nb], 0, 0, 0);                           \
      }                                                                   \
      __builtin_amdgcn_s_setprio(0);                                      \
    }                                                                     \
    LOAD_B_ALL(KTN);                                                      \
  } while (0)

  // barrier: publish ds_writes + ensure ds_reads of the buffer being
  // re-staged next step are complete. Global loads stay in flight.
#define BARRIER()                                          \
  do {                                                     \
    asm volatile("s_waitcnt lgkmcnt(0)" ::: "memory");     \
    __builtin_amdgcn_sched_barrier(0);                     \
    __builtin_amdgcn_s_barrier();                          \
  } while (0)

  // ---- prologue: B(0) in flight; A(0) -> buf0; prefetch A(1) regs ----
  LOAD_B_ALL(0);
  float4 f0 = *(const float4*)(ap);
  float4 f1 = *(const float4*)(ap + 4);
  CONV_A(f0, f1, AH0, AL0);
  float4 g0 = *(const float4*)(ap + 32);
  float4 g1 = *(const float4*)(ap + 32 + 4);
  BARRIER();

  for (int i = 0; i < 8; ++i) {
    const int kt = 2 * i;
    // even step kt: compute buf0; conv A(kt+1)->buf1; prefetch A(kt+2)
    {
      const int ktn = (kt + 2 < 16) ? (kt + 2) : 15;
      const float* xp = ap + ktn * 32;
      f0 = *(const float4*)(xp);
      f1 = *(const float4*)(xp + 4);
    }
    CONV_A(g0, g1, AH1, AL1);
    COMPUTE(AH0, AL0, kt + 1);
    BARRIER();
    // odd step kt+1: compute buf1; conv A(kt+2)->buf0; prefetch A(kt+3)
    {
      const int ktn = (kt + 3 < 16) ? (kt + 3) : 15;
      const float* xp = ap + ktn * 32;
      g0 = *(const float4*)(xp);
      g1 = *(const float4*)(xp + 4);
    }
    CONV_A(f0, f1, AH0, AL0);
    COMPUTE(AH1, AL1, (kt + 2 < 16) ? (kt + 2) : 15);
    BARRIER();
  }

  // ---------------- epilogue ----------------
  // k-acc -> LDS (f16), row-major stride 136 halfs (=272 B). 34816 B.
  _Float16* KX = smem;
  const int col0 = wcol * 32 + n;
  const int rbase = wrow * 64;
#pragma unroll
  for (int mb = 0; mb < 4; ++mb)
#pragma unroll
    for (int reg = 0; reg < 4; ++reg) {
      const int rl = rbase + mb * 16 + g * 4 + reg;
#pragma unroll
      for (int nb = 0; nb < 2; ++nb)
        KX[rl * 136 + col0 + nb * 16] = (_Float16)acck[mb][nb][reg];
    }
  __syncthreads();

  // block-boundary edges: k local row 127 and q local row 0 (f32).
  if (wrow == 1 && g == 3) {
#pragma unroll
    for (int nb = 0; nb < 2; ++nb)
      kedge[rb * 512 + cb * 128 + col0 + nb * 16] = acck[3][nb][3];
  }
  if (wrow == 0 && g == 0) {
#pragma unroll
    for (int nb = 0; nb < 2; ++nb)
      qedge[rb * 512 + cb * 128 + col0 + nb * 16] = accq[0][nb][0];
  }

  // per-row partials: ssq, ssk, dot = q[r] . k[r-1] (k from LDS, f16).
  // Local row 0's dot comes from edgedot.
#pragma unroll
  for (int mb = 0; mb < 4; ++mb) {
#pragma unroll
    for (int reg = 0; reg < 4; ++reg) {
      const int rl = rbase + mb * 16 + g * 4 + reg;
      const long row = r0 + rl;
      float sq = 0.f, sk = 0.f, dt = 0.f;
#pragma unroll
      for (int nb = 0; nb < 2; ++nb) {
        float qv = accq[mb][nb][reg];
        float kv = acck[mb][nb][reg];
        sq = fmaf(qv, qv, sq);
        sk = fmaf(kv, kv, sk);
        if (rl > 0) {
          float kp = (float)KX[(rl - 1) * 136 + col0 + nb * 16];
          dt = fmaf(qv, kp, dt);
        }
      }
#pragma unroll
      for (int m = 1; m < 16; m <<= 1) {
        sq += __shfl_xor(sq, m, 64);
        sk += __shfl_xor(sk, m, 64);
        dt += __shfl_xor(dt, m, 64);
      }
      if (n == 0) {
        atomicAdd(&ssqOut[row], sq);
        atomicAdd(&sskOut[row], sk);
        if (rl > 0) atomicAdd(&dotOut[row], dt);
      }
    }
  }
#undef LOAD_B_ALL
#undef CONV_A
#undef COMPUTE
#undef BARRIER
}

// ---------------------------------------------------------------------------
// Boundary rows (r multiple of 128, r's l != 0): dot = qedge[rb] . kedge[rb-1]
// over all 512 cols. Sole writer of dotOut for these rows.
// ---------------------------------------------------------------------------
__global__ __launch_bounds__(64) void edgedot(
    const float* __restrict__ qedge, const float* __restrict__ kedge,
    float* __restrict__ dotOut) {
  const int rb = blockIdx.x;  // 0..511
  if (rb == 0) return;
  const long row = (long)rb * 128;
  if ((row & (LL - 1)) == 0) return;  // l == 0: p forced to 1, dot unused
  const int lane = threadIdx.x;
  float dt = 0.f;
#pragma unroll
  for (int c = lane; c < 512; c += 64)
    dt = fmaf(qedge[rb * 512 + c], kedge[(rb - 1) * 512 + c], dt);
#pragma unroll
  for (int m = 1; m < 64; m <<= 1) dt += __shfl_xor(dt, m, 64);
  if (lane == 0) dotOut[row] = dt;
}

// ---------------------------------------------------------------------------
// Combine: cos from partials -> p, b_hard, fixlist.
// ---------------------------------------------------------------------------
__global__ __launch_bounds__(256) void combine(
    const float* __restrict__ ssq, const float* __restrict__ ssk,
    const float* __restrict__ dotb, float* __restrict__ dout,
    int* __restrict__ fixlist, int* __restrict__ fixcnt) {
  const int r = blockIdx.x * 256 + threadIdx.x;
  const int l = r & (LL - 1);
  float p;
  float cosv = 0.0f;
  if (l != 0) {
    float nq = fmaxf(sqrtf(ssq[r]), 1e-12f);
    float nk = fmaxf(sqrtf(ssk[r - 1]), 1e-12f);
    cosv = dotb[r] / (nq * nk);
    p = fminf(fmaxf(0.5f * (1.0f - cosv), 0.0f), 1.0f);
  } else {
    p = 1.0f;
  }
  dout[OUT_P + r] = p;
  dout[OUT_BHARD + r] = (p >= 0.5f) ? 1.0f : 0.0f;
  if (l != 0 && fabsf(cosv) < FIX_TAU) {
    int idx = atomicAdd(fixcnt, 1);
    if (idx < FIX_CAP) fixlist[idx] = r;
  }
}

// ---------------------------------------------------------------------------
// f64 recompute of borderline rows (~60 at TAU=5e-5). Wave-parallel dots:
// each wave owns e = wv, wv+4, ...; lanes cover d (coalesced W reads),
// shfl-reduce to a wave-uniform q_e/k_e, accumulate ssq/ssk/dot.
// (Old version: per-thread stride-512 W reads (uncoalesced) + 512-deep
// serial f64 chain -- ~10x slower per row.)
// ---------------------------------------------------------------------------
__global__ __launch_bounds__(256) void fixup(
    const float* __restrict__ x, const float* __restrict__ Wq,
    const float* __restrict__ Wk, float* __restrict__ dout,
    const int* __restrict__ fixlist, const int* __restrict__ fixcnt) {
  __shared__ float xr[512], xp[512];
  __shared__ double wacc[3][4];
  const int t = threadIdx.x;
  const int lane = t & 63, wv = t >> 6;
  int nfix = *fixcnt;
  if (nfix > FIX_CAP) nfix = FIX_CAP;

  for (int idx = blockIdx.x; idx < nfix; idx += gridDim.x) {
    const int r = fixlist[idx];
    for (int d = t; d < 512; d += 256) {
      xr[d] = x[(long)r * 512 + d];
      xp[d] = x[(long)(r - 1) * 512 + d];
    }
    __syncthreads();
    double ssq = 0.0, ssk = 0.0, dot = 0.0;
    for (int e = wv; e < 512; e += 4) {
      const float* wq = Wq + (long)e * 512 + lane;
      const float* wk = Wk + (long)e * 512 + lane;
      double q = 0.0, k = 0.0;
#pragma unroll
      for (int j = 0; j < 8; ++j) {
        q = fma((double)xr[lane + j * 64], (double)wq[j * 64], q);
        k = fma((double)xp[lane + j * 64], (double)wk[j * 64], k);
      }
#pragma unroll
      for (int m = 1; m < 64; m <<= 1) {
        q += __shfl_xor(q, m, 64);
        k += __shfl_xor(k, m, 64);
      }
      ssq += q * q;
      ssk += k * k;
      dot += q * k;
    }
    if (lane == 0) {
      wacc[0][wv] = ssq;
      wacc[1][wv] = ssk;
      wacc[2][wv] = dot;
    }
    __syncthreads();
    if (t == 0) {
      double SQ = wacc[0][0] + wacc[0][1] + wacc[0][2] + wacc[0][3];
      double SK = wacc[1][0] + wacc[1][1] + wacc[1][2] + wacc[1][3];
      double DT = wacc[2][0] + wacc[2][1] + wacc[2][2] + wacc[2][3];
      double nq = sqrt(SQ);
      double nk = sqrt(SK);
      if (nq < 1e-12) nq = 1e-12;
      if (nk < 1e-12) nk = 1e-12;
      float c = (float)(DT / (nq * nk));
      float p = fminf(fmaxf(0.5f * (1.0f - c), 0.0f), 1.0f);
      dout[OUT_P + r] = p;
      dout[OUT_BHARD + r] = (p >= 0.5f) ? 1.0f : 0.0f;
    }
    __syncthreads();
  }
}

// ---------------------------------------------------------------------------
// Per-batch scan (shfl-based), mask, p_compressed, sel, counts.
// ---------------------------------------------------------------------------
__global__ __launch_bounds__(256) void scanb(
    float* __restrict__ dout, int* __restrict__ sel,
    int* __restrict__ counts, float* __restrict__ sump) {
  __shared__ int wtot[4];
  __shared__ float wps[4];
  const int b = blockIdx.x;
  const int t = threadIdx.x;
  const int lane = t & 63, wv = t >> 6;
  const long base = (long)b * LL;

  int cnt = 0;
  float psum = 0.0f;
#pragma unroll 4
  for (int j = 0; j < 32; ++j) {
    int l = t * 32 + j;
    float bh = dout[OUT_BHARD + base + l];
    float pv = dout[OUT_P + base + l];
    cnt += (bh > 0.5f) ? 1 : 0;
    psum += pv;
  }
  int inc = cnt;
#pragma unroll
  for (int off = 1; off < 64; off <<= 1) {
    int u = __shfl_up(inc, off, 64);
    if (lane >= off) inc += u;
  }
  float ps = psum;
#pragma unroll
  for (int off = 1; off < 64; off <<= 1) ps += __shfl_xor(ps, off, 64);
  if (lane == 63) wtot[wv] = inc;
  if (lane == 0) wps[wv] = ps;
  __syncthreads();
  int wbase = 0, total = 0;
#pragma unroll
  for (int i = 0; i < 4; ++i) {
    int c = wtot[i];
    if (i < wv) wbase += c;
    total += c;
  }
  if (t == 0) {
    counts[b] = total;
    sump[b] = wps[0] + wps[1] + wps[2] + wps[3];
  }
  for (int j = 0; j < 32; ++j) {
    int l = t * 32 + j;
    dout[OUT_MASK + base + l] = (l < total) ? 1.0f : 0.0f;
    dout[OUT_PCOMP + base + l] = 0.0f;
  }
  __syncthreads();
  int pos = wbase + inc - cnt;  // exclusive prefix
  for (int j = 0; j < 32; ++j) {
    int l = t * 32 + j;
    float bh = dout[OUT_BHARD + base + l];
    if (bh > 0.5f) {
      dout[OUT_PCOMP + base + pos] = dout[OUT_P + base + l];
      sel[base + pos] = l;
      ++pos;
    }
  }
}

// ---------------------------------------------------------------------------
__global__ void lossk(float* __restrict__ dout, const int* __restrict__ counts,
                      const float* __restrict__ sump) {
  if (threadIdx.x == 0 && blockIdx.x == 0) {
    float fc = 0.0f, gs = 0.0f;
    for (int b = 0; b < BB; ++b) {
      fc += (float)counts[b];
      gs += sump[b];
    }
    float F = fc / (float)NROWS;
    float G = gs / (float)NROWS;
    dout[OUT_LOSS] = 1.2f * (5.0f * F * G + (1.0f - F) * (1.0f - G));
  }
}

// ---------------------------------------------------------------------------
__global__ __launch_bounds__(128) void emit(
    const float* __restrict__ x, float* __restrict__ dout,
    const int* __restrict__ sel, const int* __restrict__ counts) {
  const long bid = blockIdx.x;
  const int b = (int)(bid >> 13);
  const int j = (int)(bid & (LL - 1));
  const int cnt = counts[b];
  float4 v = make_float4(0.0f, 0.0f, 0.0f, 0.0f);
  if (j < cnt) {
    const int l = sel[((long)b << 13) + j];
    v = *(const float4*)(x + (((long)b << 13) + l) * 512 + threadIdx.x * 4);
  }
  *(float4*)(dout + OUT_COMP + (((long)b << 13) + j) * 512 + threadIdx.x * 4) = v;
}

// ---------------------------------------------------------------------------
extern "C" void kernel_launch(void* const* d_in, const int* in_sizes, int n_in,
                              void* d_out, int out_size, void* d_ws,
                              size_t ws_size, hipStream_t stream) {
  const float* x = (const float*)d_in[0];
  const float* Wq = (const float*)d_in[1];
  const float* Wk = (const float*)d_in[2];
  float* out = (float*)d_out;
  char* ws = (char*)d_ws;

  int* fixlist = (int*)(ws + WS_FIXLIST);
  int* fixcnt = (int*)(ws + WS_FIXCNT);
  int* counts = (int*)(ws + WS_COUNTS);
  float* sump = (float*)(ws + WS_SUMP);
  int* sel = (int*)(ws + WS_SEL);
  float* ssk = (float*)(ws + WS_SSK);
  float* ssq = (float*)(ws + WS_SSQ);
  float* dotb = (float*)(ws + WS_DOT);
  _Float16* wqh = (_Float16*)(ws + WS_WQH);
  _Float16* wkh = (_Float16*)(ws + WS_WKH);

  // edge buffers (512x512 f32 each = 1 MB) staged in d_out's compressed
  // region; emit overwrites it at the end.
  float* kedge = (float*)(out + OUT_COMP);
  float* qedge = (float*)(out + OUT_COMP + 262144);

  wsplit<<<256, 256, 0, stream>>>(Wq, Wk, wqh, wkh, ssk, ssq, dotb, fixcnt);
  gemm_fused<<<2048, 512, 0, stream>>>(x, wqh, wkh, ssq, ssk, dotb, qedge, kedge);
  edgedot<<<512, 64, 0, stream>>>(qedge, kedge, dotb);
  combine<<<NROWS / 256, 256, 0, stream>>>(ssq, ssk, dotb, out, fixlist, fixcnt);
  fixup<<<512, 256, 0, stream>>>(x, Wq, Wk, out, fixlist, fixcnt);
  scanb<<<BB, 256, 0, stream>>>(out, sel, counts, sump);
  lossk<<<1, 64, 0, stream>>>(out, counts, sump);
  emit<<<NROWS, 128, 0, stream>>>(x, out, sel, counts);
}

// Round 7
// 447.141 us; speedup vs baseline: 1.1645x; 1.1645x over previous
//
#include <hip/hip_runtime.h>
#include <hip/hip_bf16.h>
#include <math.h>

// Problem constants
#define BB 8
#define LL 8192
#define DD 512
#define NROWS (BB * LL)  // 65536

// d_out layout (floats)
#define OUT_COMP   0
#define OUT_MASK   33554432
#define OUT_BHARD  33619968
#define OUT_P      33685504
#define OUT_PCOMP  33751040
#define OUT_LOSS   33816576

// ws layout (bytes)
#define WS_FIXLIST 0         // 65536*4
#define WS_FIXCNT  262144    // 4
#define WS_COUNTS  262148    // 32
#define WS_SUMP    262180    // 32
#define WS_SEL     262212    // 65536*4 -> 524356
#define WS_SSK     524416    // 65536*4
#define WS_SSQ     786560    // 65536*4
#define WS_DOT     1048704   // 65536*4
#define WS_WQH     1310848   // 512 KB each
#define WS_WKH     1835136   // end ~2.4 MB

#define FIX_CAP 65536
// pure-f16 GEMM cos error rms ~2.1e-5 (A+B f16 rounding + f16 KX dot path);
// tau = 1.5e-4 = 7 sigma flip margin, ~200 fixup rows (cheap, wave-parallel).
#define FIX_TAU 1.5e-4f

typedef __attribute__((ext_vector_type(8))) _Float16 half8;
typedef __attribute__((ext_vector_type(4))) float f32x4;

// async global->LDS, 16 B per lane; lds base wave-uniform, data lands at
// lds + lane*16 (m104/m108).
static __device__ __forceinline__ void ld_g2l16(const void* g, void* l) {
  __builtin_amdgcn_global_load_lds(
      (const __attribute__((address_space(1))) void*)g,
      (__attribute__((address_space(3))) void*)l, 16, 0, 0);
}

// ---------------------------------------------------------------------------
// Pass 0: split Wq,Wk into f16 (pure-f16 GEMM), fragment-chunk order:
// chunk c = (kt*32 + ct)*64 + kblk*16 + n holds W[e=ct*16+n][d=kt*32+kblk*8..+8].
// Also zero-inits accumulators. A lane's B-fragment = one contiguous 16 B load.
// ---------------------------------------------------------------------------
__global__ __launch_bounds__(256) void wsplit(
    const float* __restrict__ Wq, const float* __restrict__ Wk,
    _Float16* __restrict__ wqh, _Float16* __restrict__ wkh,
    float* __restrict__ ssk, float* __restrict__ ssq,
    float* __restrict__ dotb, int* __restrict__ fixcnt) {
  const int t = blockIdx.x * 256 + threadIdx.x;  // 0..65535
  if (t == 0) *fixcnt = 0;
  ssk[t] = 0.0f;
  ssq[t] = 0.0f;
  dotb[t] = 0.0f;

  const int m = t >> 15;         // 0 = Wq, 1 = Wk
  const int c = t & 32767;       // chunk id
  const int kt = c >> 11;
  const int ct = (c >> 6) & 31;
  const int l = c & 63;
  const int n = l & 15;
  const int kblk = l >> 4;
  const int e = ct * 16 + n;
  const int d0 = kt * 32 + kblk * 8;
  const float* src = (m ? Wk : Wq) + (long)e * 512 + d0;
  _Float16* dh = (m ? wkh : wqh) + (long)c * 8;
  float4 v0 = *(const float4*)src;
  float4 v1 = *(const float4*)(src + 4);
  float av[8] = {v0.x, v0.y, v0.z, v0.w, v1.x, v1.y, v1.z, v1.w};
  half8 hi;
#pragma unroll
  for (int j = 0; j < 8; ++j) hi[j] = (_Float16)av[j];
  *(half8*)dh = hi;
}

// ---------------------------------------------------------------------------
// FUSED GEMM: q = x*Wq^T and k = x*Wk^T, PURE f16 (1-pairing; precision
// covered by widened-tau f64 fixup). 128x128 tile, 4 waves 2x2.
// BK=64 phases: 2 K-tiles per barrier -> 9 barriers total, 64 MFMA per wave
// per phase (rounds 4-6 ablations: 2-phase-per-barrier structure stalls ~70%
// independent of LDS traffic / vmcnt pipelining / occupancy; the levers left
// are work-halving + fewer barriers).
//  - A: raw f32 via global_load_lds, phase buffer = 2 x 16KB kt-halves, each
//    the proven round-5 swizzled layout (row stride 128 B, byte^=(row&7)<<4,
//    inverse-swizzle on the global source, swizzled ds_read). f32->f16
//    truncation at read time (8 cvt per frag, no lo).
//  - B: global->reg (fragment-chunk order, L2-resident), two named sets
//    (kt-even / kt-odd), each reloaded right after its last MFMA use.
//  - Barrier: s_waitcnt vmcnt(16) drains exactly my 8 A-g2l (oldest); the
//    16 B reloads stay in flight across it. lgkmcnt(0) closes A-buf WAR.
// ---------------------------------------------------------------------------
__global__ __launch_bounds__(256, 2) void gemm_fused(
    const float* __restrict__ x,
    const _Float16* __restrict__ wqh, const _Float16* __restrict__ wkh,
    float* __restrict__ ssqOut, float* __restrict__ sskOut,
    float* __restrict__ dotOut,
    float* __restrict__ qedge, float* __restrict__ kedge) {
  __shared__ float smemf[16384];  // 64 KB: two 32 KB phase buffers
  float* A0 = smemf;              // each: [ktp][128 rows][32 f32 swizzled]
  float* A1 = smemf + 8192;

  const int tid = threadIdx.x;
  const int lane = tid & 63;
  const int w = tid >> 6;
  const int wrow = w & 1, wcol = w >> 1;
  const int g = lane >> 4, n = lane & 15;
  const int bx0 = blockIdx.x;
  const int bx = ((bx0 & 7) << 8) | (bx0 >> 3);  // XCD-contiguous (2048 = 8*256)
  const int rb = bx >> 2, cb = bx & 3;
  const long r0 = (long)rb * 128;

  // ---- A staging map (per kt-half; same as round 5) ----
  // wave w, call jj (0..3): 1 KB at half_base + (w*4+jj)*1024, lane*16.
  // phys row = w*32 + jj*8 + (lane>>3); logical col = phys ^ ((row&7)<<4).
  const int srow = w * 32 + (lane >> 3);              // + jj*8
  const int scol = ((lane & 7) ^ (lane >> 3)) << 2;   // float index
  const float* gsrc0 = x + (r0 + srow) * 512 + scol;  // + jj*8*512 + p*64 + ktp*32

  // ---- A read map: row(mb) = wrow*64 + mb*16 + (lane&15); row&7 = lane&7;
  // frag bytes [kb0, +32) logical, kb0 = (lane>>4)*32.
  const int sw = (lane & 7) << 4;
  const int kb0 = (lane >> 4) << 5;
  const int o1 = kb0 ^ sw;
  const int o2 = (kb0 + 16) ^ sw;
  const int rdrow0 = wrow * 64 + (lane & 15);

  // ---- B fragment bases (fragment-chunk order; 16 B per lane) ----
  const _Float16* bqb = wqh + ((long)((cb * 8 + wcol * 4) * 64 + lane)) * 8;
  const _Float16* bkb = wkh + ((long)((cb * 8 + wcol * 4) * 64 + lane)) * 8;

  f32x4 accq[4][4], acck[4][4];
#pragma unroll
  for (int mb = 0; mb < 4; ++mb)
#pragma unroll
    for (int nb = 0; nb < 4; ++nb) {
      accq[mb][nb] = (f32x4){0.f, 0.f, 0.f, 0.f};
      acck[mb][nb] = (f32x4){0.f, 0.f, 0.f, 0.f};
    }

  half8 bq0[4], bk0[4], bq1[4], bk1[4];  // two named B sets (kt even / odd)

#define STAGE_A(pv, BUF)                                                  \
  do {                                                                    \
    _Pragma("unroll") for (int j = 0; j < 8; ++j) {                       \
      const int ktp_ = j >> 2, jj_ = j & 3;                               \
      ld_g2l16(gsrc0 + (long)jj_ * 8 * 512 + (pv)*64 + ktp_ * 32,         \
               (char*)(BUF) + ktp_ * 16384 + (w * 4 + jj_) * 1024);       \
    }                                                                     \
  } while (0)

#define LOAD_B(BQ_, BK_, ktv)                                             \
  do {                                                                    \
    _Pragma("unroll") for (int nb = 0; nb < 4; ++nb) {                    \
      BQ_[nb] = *(const half8*)(bqb + (long)(ktv)*16384 + nb * 512);      \
      BK_[nb] = *(const half8*)(bkb + (long)(ktv)*16384 + nb * 512);      \
    }                                                                     \
  } while (0)

  // COMPUTE one kt-half: 8 ds_read_b128 + 32 cvt + 32 MFMA; then reload
  // this half's B set for K-tile KTN.
#define COMPUTE(BUF, KTP, BQ_, BK_, KTN)                                  \
  do {                                                                    \
    half8 ah[4];                                                          \
    _Pragma("unroll") for (int mb = 0; mb < 4; ++mb) {                    \
      const char* rp =                                                    \
          (const char*)((BUF) + (KTP)*4096 + (rdrow0 + mb * 16) * 32);    \
      float4 v0 = *(const float4*)(rp + o1);                              \
      float4 v1 = *(const float4*)(rp + o2);                              \
      float av[8] = {v0.x, v0.y, v0.z, v0.w, v1.x, v1.y, v1.z, v1.w};     \
      half8 h;                                                            \
      _Pragma("unroll") for (int j = 0; j < 8; ++j) h[j] = (_Float16)av[j]; \
      ah[mb] = h;                                                         \
    }                                                                     \
    __builtin_amdgcn_s_setprio(1);                                        \
    _Pragma("unroll") for (int nb = 0; nb < 4; ++nb)                      \
        _Pragma("unroll") for (int mb = 0; mb < 4; ++mb) {                \
      accq[mb][nb] = __builtin_amdgcn_mfma_f32_16x16x32_f16(              \
          ah[mb], BQ_[nb], accq[mb][nb], 0, 0, 0);                        \
      acck[mb][nb] = __builtin_amdgcn_mfma_f32_16x16x32_f16(              \
          ah[mb], BK_[nb], acck[mb][nb], 0, 0, 0);                        \
    }                                                                     \
    __builtin_amdgcn_s_setprio(0);                                        \
    LOAD_B(BQ_, BK_, KTN);                                                \
  } while (0)

  // counted barrier: drain MY 8 A-g2l (oldest vmem), leave the 16 B reloads
  // in flight; lgkmcnt(0) orders ds_reads before the buffer is re-staged.
#define BARRIER_CNT()                                       \
  do {                                                      \
    asm volatile("s_waitcnt vmcnt(16)" ::: "memory");       \
    asm volatile("s_waitcnt lgkmcnt(0)" ::: "memory");      \
    __builtin_amdgcn_sched_barrier(0);                      \
    __builtin_amdgcn_s_barrier();                           \
  } while (0)

#define FENCE() __builtin_amdgcn_sched_barrier(0)

  // ---- prologue: A(phase 0) g2l (oldest), B(0),B(1) -> regs ----
  STAGE_A(0, A0);
  FENCE();
  LOAD_B(bq0, bk0, 0);
  LOAD_B(bq1, bk1, 1);
  FENCE();
  BARRIER_CNT();  // A(0) staged; 16 B loads in flight

  {
    float* cur = A0;
    float* nxt = A1;
    for (int p = 0; p < 8; ++p) {
      if (p < 7) STAGE_A(p + 1, nxt);
      FENCE();
      const int ktn0 = (2 * p + 2 < 16) ? 2 * p + 2 : 15;
      const int ktn1 = (2 * p + 3 < 16) ? 2 * p + 3 : 15;
      COMPUTE(cur, 0, bq0, bk0, ktn0);
      COMPUTE(cur, 1, bq1, bk1, ktn1);
      BARRIER_CNT();
      float* t = cur;
      cur = nxt;
      nxt = t;
    }
  }

  // ---------------- epilogue ----------------
  // (loop's final barrier synced all waves; no g2l pending -> smem reusable)
  // k-acc -> LDS (f16), row-major stride 136 halfs (=272 B). 34816 B.
  _Float16* KX = (_Float16*)smemf;
  const int col0 = wcol * 64 + n;
  const int rbase = wrow * 64;
#pragma unroll
  for (int mb = 0; mb < 4; ++mb)
#pragma unroll
    for (int reg = 0; reg < 4; ++reg) {
      const int rl = rbase + mb * 16 + g * 4 + reg;
#pragma unroll
      for (int nb = 0; nb < 4; ++nb)
        KX[rl * 136 + col0 + nb * 16] = (_Float16)acck[mb][nb][reg];
    }
  __syncthreads();

  // block-boundary edges: k local row 127 and q local row 0 (f32, 128 cols
  // per (rb,cb) block -> full 512 cols per rb across cb).
  if (wrow == 1 && g == 3) {
#pragma unroll
    for (int nb = 0; nb < 4; ++nb)
      kedge[rb * 512 + cb * 128 + col0 + nb * 16] = acck[3][nb][3];
  }
  if (wrow == 0 && g == 0) {
#pragma unroll
    for (int nb = 0; nb < 4; ++nb)
      qedge[rb * 512 + cb * 128 + col0 + nb * 16] = accq[0][nb][0];
  }

  // per-row partials: ssq, ssk, dot = q[r] . k[r-1] (k from LDS, f16).
  // Local row 0's dot comes from edgedot.
#pragma unroll
  for (int mb = 0; mb < 4; ++mb) {
#pragma unroll
    for (int reg = 0; reg < 4; ++reg) {
      const int rl = rbase + mb * 16 + g * 4 + reg;
      const long row = r0 + rl;
      float sq = 0.f, sk = 0.f, dt = 0.f;
#pragma unroll
      for (int nb = 0; nb < 4; ++nb) {
        float qv = accq[mb][nb][reg];
        float kv = acck[mb][nb][reg];
        sq = fmaf(qv, qv, sq);
        sk = fmaf(kv, kv, sk);
        if (rl > 0) {
          float kp = (float)KX[(rl - 1) * 136 + col0 + nb * 16];
          dt = fmaf(qv, kp, dt);
        }
      }
#pragma unroll
      for (int m = 1; m < 16; m <<= 1) {
        sq += __shfl_xor(sq, m, 64);
        sk += __shfl_xor(sk, m, 64);
        dt += __shfl_xor(dt, m, 64);
      }
      if (n == 0) {
        atomicAdd(&ssqOut[row], sq);
        atomicAdd(&sskOut[row], sk);
        if (rl > 0) atomicAdd(&dotOut[row], dt);
      }
    }
  }
#undef STAGE_A
#undef LOAD_B
#undef COMPUTE
#undef BARRIER_CNT
#undef FENCE
}

// ---------------------------------------------------------------------------
// Boundary rows (r multiple of 128, r's l != 0): dot = qedge[rb] . kedge[rb-1]
// over all 512 cols. Sole writer of dotOut for these rows.
// ---------------------------------------------------------------------------
__global__ __launch_bounds__(64) void edgedot(
    const float* __restrict__ qedge, const float* __restrict__ kedge,
    float* __restrict__ dotOut) {
  const int rb = blockIdx.x;  // 0..511
  if (rb == 0) return;
  const long row = (long)rb * 128;
  if ((row & (LL - 1)) == 0) return;  // l == 0: p forced to 1, dot unused
  const int lane = threadIdx.x;
  float dt = 0.f;
#pragma unroll
  for (int c = lane; c < 512; c += 64)
    dt = fmaf(qedge[rb * 512 + c], kedge[(rb - 1) * 512 + c], dt);
#pragma unroll
  for (int m = 1; m < 64; m <<= 1) dt += __shfl_xor(dt, m, 64);
  if (lane == 0) dotOut[row] = dt;
}

// ---------------------------------------------------------------------------
// Combine: cos from partials -> p, b_hard, fixlist.
// ---------------------------------------------------------------------------
__global__ __launch_bounds__(256) void combine(
    const float* __restrict__ ssq, const float* __restrict__ ssk,
    const float* __restrict__ dotb, float* __restrict__ dout,
    int* __restrict__ fixlist, int* __restrict__ fixcnt) {
  const int r = blockIdx.x * 256 + threadIdx.x;
  const int l = r & (LL - 1);
  float p;
  float cosv = 0.0f;
  if (l != 0) {
    float nq = fmaxf(sqrtf(ssq[r]), 1e-12f);
    float nk = fmaxf(sqrtf(ssk[r - 1]), 1e-12f);
    cosv = dotb[r] / (nq * nk);
    p = fminf(fmaxf(0.5f * (1.0f - cosv), 0.0f), 1.0f);
  } else {
    p = 1.0f;
  }
  dout[OUT_P + r] = p;
  dout[OUT_BHARD + r] = (p >= 0.5f) ? 1.0f : 0.0f;
  if (l != 0 && fabsf(cosv) < FIX_TAU) {
    int idx = atomicAdd(fixcnt, 1);
    if (idx < FIX_CAP) fixlist[idx] = r;
  }
}

// ---------------------------------------------------------------------------
// f64 recompute of borderline rows (~200 at TAU=1.5e-4). Wave-parallel:
// each wave owns e = wv, wv+4, ...; lanes cover d (coalesced W reads),
// shfl-reduce to wave-uniform q_e/k_e, accumulate ssq/ssk/dot.
// ---------------------------------------------------------------------------
__global__ __launch_bounds__(256) void fixup(
    const float* __restrict__ x, const float* __restrict__ Wq,
    const float* __restrict__ Wk, float* __restrict__ dout,
    const int* __restrict__ fixlist, const int* __restrict__ fixcnt) {
  __shared__ float xr[512], xp[512];
  __shared__ double wacc[3][4];
  const int t = threadIdx.x;
  const int lane = t & 63, wv = t >> 6;
  int nfix = *fixcnt;
  if (nfix > FIX_CAP) nfix = FIX_CAP;

  for (int idx = blockIdx.x; idx < nfix; idx += gridDim.x) {
    const int r = fixlist[idx];
    for (int d = t; d < 512; d += 256) {
      xr[d] = x[(long)r * 512 + d];
      xp[d] = x[(long)(r - 1) * 512 + d];
    }
    __syncthreads();
    double ssq = 0.0, ssk = 0.0, dot = 0.0;
    for (int e = wv; e < 512; e += 4) {
      const float* wq = Wq + (long)e * 512 + lane;
      const float* wk = Wk + (long)e * 512 + lane;
      double q = 0.0, k = 0.0;
#pragma unroll
      for (int j = 0; j < 8; ++j) {
        q = fma((double)xr[lane + j * 64], (double)wq[j * 64], q);
        k = fma((double)xp[lane + j * 64], (double)wk[j * 64], k);
      }
#pragma unroll
      for (int m = 1; m < 64; m <<= 1) {
        q += __shfl_xor(q, m, 64);
        k += __shfl_xor(k, m, 64);
      }
      ssq += q * q;
      ssk += k * k;
      dot += q * k;
    }
    if (lane == 0) {
      wacc[0][wv] = ssq;
      wacc[1][wv] = ssk;
      wacc[2][wv] = dot;
    }
    __syncthreads();
    if (t == 0) {
      double SQ = wacc[0][0] + wacc[0][1] + wacc[0][2] + wacc[0][3];
      double SK = wacc[1][0] + wacc[1][1] + wacc[1][2] + wacc[1][3];
      double DT = wacc[2][0] + wacc[2][1] + wacc[2][2] + wacc[2][3];
      double nq = sqrt(SQ);
      double nk = sqrt(SK);
      if (nq < 1e-12) nq = 1e-12;
      if (nk < 1e-12) nk = 1e-12;
      float c = (float)(DT / (nq * nk));
      float p = fminf(fmaxf(0.5f * (1.0f - c), 0.0f), 1.0f);
      dout[OUT_P + r] = p;
      dout[OUT_BHARD + r] = (p >= 0.5f) ? 1.0f : 0.0f;
    }
    __syncthreads();
  }
}

// ---------------------------------------------------------------------------
// Per-batch scan (shfl-based), mask, p_compressed, sel, counts.
// ---------------------------------------------------------------------------
__global__ __launch_bounds__(256) void scanb(
    float* __restrict__ dout, int* __restrict__ sel,
    int* __restrict__ counts, float* __restrict__ sump) {
  __shared__ int wtot[4];
  __shared__ float wps[4];
  const int b = blockIdx.x;
  const int t = threadIdx.x;
  const int lane = t & 63, wv = t >> 6;
  const long base = (long)b * LL;

  int cnt = 0;
  float psum = 0.0f;
#pragma unroll 4
  for (int j = 0; j < 32; ++j) {
    int l = t * 32 + j;
    float bh = dout[OUT_BHARD + base + l];
    float pv = dout[OUT_P + base + l];
    cnt += (bh > 0.5f) ? 1 : 0;
    psum += pv;
  }
  int inc = cnt;
#pragma unroll
  for (int off = 1; off < 64; off <<= 1) {
    int u = __shfl_up(inc, off, 64);
    if (lane >= off) inc += u;
  }
  float ps = psum;
#pragma unroll
  for (int off = 1; off < 64; off <<= 1) ps += __shfl_xor(ps, off, 64);
  if (lane == 63) wtot[wv] = inc;
  if (lane == 0) wps[wv] = ps;
  __syncthreads();
  int wbase = 0, total = 0;
#pragma unroll
  for (int i = 0; i < 4; ++i) {
    int c = wtot[i];
    if (i < wv) wbase += c;
    total += c;
  }
  if (t == 0) {
    counts[b] = total;
    sump[b] = wps[0] + wps[1] + wps[2] + wps[3];
  }
  for (int j = 0; j < 32; ++j) {
    int l = t * 32 + j;
    dout[OUT_MASK + base + l] = (l < total) ? 1.0f : 0.0f;
    dout[OUT_PCOMP + base + l] = 0.0f;
  }
  __syncthreads();
  int pos = wbase + inc - cnt;  // exclusive prefix
  for (int j = 0; j < 32; ++j) {
    int l = t * 32 + j;
    float bh = dout[OUT_BHARD + base + l];
    if (bh > 0.5f) {
      dout[OUT_PCOMP + base + pos] = dout[OUT_P + base + l];
      sel[base + pos] = l;
      ++pos;
    }
  }
}

// ---------------------------------------------------------------------------
__global__ void lossk(float* __restrict__ dout, const int* __restrict__ counts,
                      const float* __restrict__ sump) {
  if (threadIdx.x == 0 && blockIdx.x == 0) {
    float fc = 0.0f, gs = 0.0f;
    for (int b = 0; b < BB; ++b) {
      fc += (float)counts[b];
      gs += sump[b];
    }
    float F = fc / (float)NROWS;
    float G = gs / (float)NROWS;
    dout[OUT_LOSS] = 1.2f * (5.0f * F * G + (1.0f - F) * (1.0f - G));
  }
}

// ---------------------------------------------------------------------------
__global__ __launch_bounds__(128) void emit(
    const float* __restrict__ x, float* __restrict__ dout,
    const int* __restrict__ sel, const int* __restrict__ counts) {
  const long bid = blockIdx.x;
  const int b = (int)(bid >> 13);
  const int j = (int)(bid & (LL - 1));
  const int cnt = counts[b];
  float4 v = make_float4(0.0f, 0.0f, 0.0f, 0.0f);
  if (j < cnt) {
    const int l = sel[((long)b << 13) + j];
    v = *(const float4*)(x + (((long)b << 13) + l) * 512 + threadIdx.x * 4);
  }
  *(float4*)(dout + OUT_COMP + (((long)b << 13) + j) * 512 + threadIdx.x * 4) = v;
}

// ---------------------------------------------------------------------------
extern "C" void kernel_launch(void* const* d_in, const int* in_sizes, int n_in,
                              void* d_out, int out_size, void* d_ws,
                              size_t ws_size, hipStream_t stream) {
  const float* x = (const float*)d_in[0];
  const float* Wq = (const float*)d_in[1];
  const float* Wk = (const float*)d_in[2];
  float* out = (float*)d_out;
  char* ws = (char*)d_ws;

  int* fixlist = (int*)(ws + WS_FIXLIST);
  int* fixcnt = (int*)(ws + WS_FIXCNT);
  int* counts = (int*)(ws + WS_COUNTS);
  float* sump = (float*)(ws + WS_SUMP);
  int* sel = (int*)(ws + WS_SEL);
  float* ssk = (float*)(ws + WS_SSK);
  float* ssq = (float*)(ws + WS_SSQ);
  float* dotb = (float*)(ws + WS_DOT);
  _Float16* wqh = (_Float16*)(ws + WS_WQH);
  _Float16* wkh = (_Float16*)(ws + WS_WKH);

  // edge buffers (512x512 f32 each = 1 MB) staged in d_out's compressed
  // region; emit overwrites it at the end.
  float* kedge = (float*)(out + OUT_COMP);
  float* qedge = (float*)(out + OUT_COMP + 262144);

  wsplit<<<256, 256, 0, stream>>>(Wq, Wk, wqh, wkh, ssk, ssq, dotb, fixcnt);
  gemm_fused<<<2048, 256, 0, stream>>>(x, wqh, wkh, ssq, ssk, dotb, qedge, kedge);
  edgedot<<<512, 64, 0, stream>>>(qedge, kedge, dotb);
  combine<<<NROWS / 256, 256, 0, stream>>>(ssq, ssk, dotb, out, fixlist, fixcnt);
  fixup<<<512, 256, 0, stream>>>(x, Wq, Wk, out, fixlist, fixcnt);
  scanb<<<BB, 256, 0, stream>>>(out, sel, counts, sump);
  lossk<<<1, 64, 0, stream>>>(out, counts, sump);
  emit<<<NROWS, 128, 0, stream>>>(x, out, sel, counts);
}